// Round 1
// baseline (678.711 us; speedup 1.0000x reference)
//
#include <hip/hip_runtime.h>
#include <hip/hip_bf16.h>

// Batched COO SpMM: out[k, row[e], f] += values[k][e] * b[k][col[e]][f]
// B=4, NNZ=800000, M=N=50000, F=64.
// Baseline: one wave (64 lanes) per (edge, batch) task; lane = feature.
// 64 lanes x 4B = 256B coalesced gather from b and coalesced atomic scatter
// to out. Grid-stride over tasks.

#define FEAT 64

__global__ __launch_bounds__(256) void spmm_atomic_kernel(
    const int* __restrict__ indices,   // [2][nnz] : row, col
    const float* __restrict__ values,  // [batch][nnz]
    const float* __restrict__ b,       // [batch][m][FEAT]
    float* __restrict__ out,           // [batch][m][FEAT]
    int nnz, int m, int ntasks)
{
    const int lane = threadIdx.x & 63;
    const int waves_per_block = blockDim.x >> 6;
    const int nwaves = gridDim.x * waves_per_block;
    int wave = blockIdx.x * waves_per_block + (threadIdx.x >> 6);

    for (int task = wave; task < ntasks; task += nwaves) {
        const int e = task >> 2;       // batch = 4 (power of two)
        const int k = task & 3;
        const int row = indices[e];
        const int col = indices[nnz + e];
        const float v = values[(size_t)k * nnz + e];
        const float contrib = v * b[((size_t)k * m + col) * FEAT + lane];
        unsafeAtomicAdd(&out[((size_t)k * m + row) * FEAT + lane], contrib);
    }
}

extern "C" void kernel_launch(void* const* d_in, const int* in_sizes, int n_in,
                              void* d_out, int out_size, void* d_ws, size_t ws_size,
                              hipStream_t stream) {
    const int* indices  = (const int*)d_in[0];     // [2, nnz]
    const float* values = (const float*)d_in[1];   // [batch, nnz]
    // d_in[2] = shape_m (device scalar), d_in[3] = shape_n (device scalar)
    const float* b      = (const float*)d_in[4];   // [batch, m, FEAT]
    float* out          = (float*)d_out;

    const int nnz   = in_sizes[0] / 2;
    const int batch = in_sizes[1] / nnz;           // = 4
    const int m     = out_size / (batch * FEAT);   // = 50000
    const int ntasks = nnz * batch;

    // Harness poisons d_out once (0xAA) and never re-poisons between timed
    // replays -> we must zero it ourselves every call.
    hipMemsetAsync(d_out, 0, (size_t)out_size * sizeof(float), stream);

    const int block = 256;                          // 4 waves
    const int grid  = 2048;                         // ~8 blocks/CU, grid-stride
    spmm_atomic_kernel<<<grid, block, 0, stream>>>(indices, values, b, out,
                                                   nnz, m, ntasks);
}

// Round 2
// 329.031 us; speedup vs baseline: 2.0628x; 2.0628x over previous
//
#include <hip/hip_runtime.h>
#include <hip/hip_bf16.h>

// Batched COO SpMM: out[k, row[e], f] = sum_e values[k][e] * b[k][col[e]][f]
// B=4, NNZ=800000, M=N=50000, F=64.
//
// Round 2: device-side CSR build (histogram + single-block scan + counting
// sort permutation) in d_ws, then atomic-free SpMM: one wave per row,
// lane = feature, 4 batch accumulators in registers, plain stores.
// Kills the 819 MB of atomic write traffic seen in round 1.

#define FEAT 64
#define SCAN_THREADS 1024

// ---------- preprocessing ----------

__global__ void hist_kernel(const int* __restrict__ rows,
                            int* __restrict__ counts, int nnz) {
    int i = blockIdx.x * blockDim.x + threadIdx.x;
    const int stride = gridDim.x * blockDim.x;
    for (; i < nnz; i += stride) atomicAdd(&counts[rows[i]], 1);
}

__global__ __launch_bounds__(SCAN_THREADS) void scan_kernel(
    const int* __restrict__ counts, int* __restrict__ row_ptr,
    int* __restrict__ cursor, int m, int nnz) {
    __shared__ int bufA[SCAN_THREADS];
    __shared__ int bufB[SCAN_THREADS];
    const int t = threadIdx.x;
    const int chunk = (m + SCAN_THREADS - 1) / SCAN_THREADS;
    const int lo = t * chunk;
    const int hi = min(lo + chunk, m);

    int s = 0;
    for (int i = lo; i < hi; ++i) s += counts[i];
    bufA[t] = s;
    __syncthreads();

    // Hillis-Steele inclusive scan over 1024 partials (ping-pong buffers).
    int* src = bufA;
    int* dst = bufB;
    for (int off = 1; off < SCAN_THREADS; off <<= 1) {
        int v = src[t];
        if (t >= off) v += src[t - off];
        dst[t] = v;
        __syncthreads();
        int* tmp = src; src = dst; dst = tmp;
    }

    int base = (t == 0) ? 0 : src[t - 1];
    for (int i = lo; i < hi; ++i) {
        row_ptr[i] = base;
        cursor[i]  = base;
        base += counts[i];
    }
    if (t == 0) row_ptr[m] = nnz;
}

// Counting-sort the edges by row; also gather per-batch values into sorted
// order so the SpMM loop reads col/val sequentially (scalar-friendly).
__global__ void permute_kernel(const int* __restrict__ indices,
                               const float* __restrict__ values,
                               int* __restrict__ cursor,
                               int* __restrict__ col_sorted,
                               float* __restrict__ val_sorted, int nnz) {
    int i = blockIdx.x * blockDim.x + threadIdx.x;
    const int stride = gridDim.x * blockDim.x;
    for (; i < nnz; i += stride) {
        const int r = indices[i];
        const int c = indices[nnz + i];
        const int pos = atomicAdd(&cursor[r], 1);
        col_sorted[pos] = c;
#pragma unroll
        for (int k = 0; k < 4; ++k)
            val_sorted[(size_t)k * nnz + pos] = values[(size_t)k * nnz + i];
    }
}

// ---------- main SpMM (atomic-free) ----------
// One wave per row; lane = feature; 4 batch accumulators in registers.
__global__ __launch_bounds__(256) void spmm_csr_kernel(
    const int* __restrict__ row_ptr, const int* __restrict__ col_sorted,
    const float* __restrict__ val_sorted, const float* __restrict__ b,
    float* __restrict__ out, int m, int nnz) {
    const int lane = threadIdx.x & 63;
    const int wave = blockIdx.x * (blockDim.x >> 6) + (threadIdx.x >> 6);
    if (wave >= m) return;
    const int row   = __builtin_amdgcn_readfirstlane(wave);
    const int start = row_ptr[row];
    const int end   = row_ptr[row + 1];

    const size_t bm = (size_t)m * FEAT;
    float acc0 = 0.f, acc1 = 0.f, acc2 = 0.f, acc3 = 0.f;
    for (int j = start; j < end; ++j) {
        const int c = col_sorted[j];
        const size_t cb = (size_t)c * FEAT + lane;
        const float v0 = val_sorted[j];
        const float v1 = val_sorted[(size_t)nnz + j];
        const float v2 = val_sorted[2 * (size_t)nnz + j];
        const float v3 = val_sorted[3 * (size_t)nnz + j];
        acc0 += v0 * b[cb];
        acc1 += v1 * b[bm + cb];
        acc2 += v2 * b[2 * bm + cb];
        acc3 += v3 * b[3 * bm + cb];
    }
    const size_t o = (size_t)row * FEAT + lane;
    out[o]          = acc0;
    out[bm + o]     = acc1;
    out[2 * bm + o] = acc2;
    out[3 * bm + o] = acc3;
}

// ---------- fallback (round-1 atomic version, used only if ws too small) ----
__global__ __launch_bounds__(256) void spmm_atomic_kernel(
    const int* __restrict__ indices, const float* __restrict__ values,
    const float* __restrict__ b, float* __restrict__ out,
    int nnz, int m, int batch, int ntasks) {
    const int lane = threadIdx.x & 63;
    const int waves_per_block = blockDim.x >> 6;
    const int nwaves = gridDim.x * waves_per_block;
    int wave = blockIdx.x * waves_per_block + (threadIdx.x >> 6);
    for (int task = wave; task < ntasks; task += nwaves) {
        const int e = task / batch;
        const int k = task - e * batch;
        const int row = indices[e];
        const int col = indices[nnz + e];
        const float v = values[(size_t)k * nnz + e];
        const float contrib = v * b[((size_t)k * m + col) * FEAT + lane];
        unsafeAtomicAdd(&out[((size_t)k * m + row) * FEAT + lane], contrib);
    }
}

extern "C" void kernel_launch(void* const* d_in, const int* in_sizes, int n_in,
                              void* d_out, int out_size, void* d_ws, size_t ws_size,
                              hipStream_t stream) {
    const int* indices  = (const int*)d_in[0];    // [2, nnz]
    const float* values = (const float*)d_in[1];  // [batch, nnz]
    const float* b      = (const float*)d_in[4];  // [batch, m, FEAT]
    float* out          = (float*)d_out;

    const int nnz   = in_sizes[0] / 2;
    const int batch = in_sizes[1] / nnz;
    const int m     = out_size / (batch * FEAT);

    // ws layout (ints/floats, 4B):
    //   counts     [0, m)
    //   row_ptr    [m, 2m+1)
    //   cursor     [2m+1, 3m+1)
    //   col_sorted [3m+1, 3m+1+nnz)
    //   val_sorted [3m+1+nnz, 3m+1+nnz+4*nnz)
    const size_t need = ((size_t)3 * m + 1 + (size_t)5 * nnz) * 4;

    if (batch != 4 || ws_size < need) {
        // fallback: round-1 atomic path
        hipMemsetAsync(d_out, 0, (size_t)out_size * sizeof(float), stream);
        spmm_atomic_kernel<<<2048, 256, 0, stream>>>(indices, values, b, out,
                                                     nnz, m, batch, nnz * batch);
        return;
    }

    int* counts      = (int*)d_ws;
    int* row_ptr     = counts + m;
    int* cursor      = row_ptr + m + 1;
    int* col_sorted  = cursor + m;
    float* val_sorted = (float*)(col_sorted + nnz);

    hipMemsetAsync(counts, 0, (size_t)m * sizeof(int), stream);
    hist_kernel<<<1024, 256, 0, stream>>>(indices, counts, nnz);
    scan_kernel<<<1, SCAN_THREADS, 0, stream>>>(counts, row_ptr, cursor, m, nnz);
    permute_kernel<<<1024, 256, 0, stream>>>(indices, values, cursor,
                                             col_sorted, val_sorted, nnz);

    const int waves_per_block = 4;  // 256 threads
    const int grid = (m + waves_per_block - 1) / waves_per_block;
    spmm_csr_kernel<<<grid, 256, 0, stream>>>(row_ptr, col_sorted, val_sorted,
                                              b, out, m, nnz);
}

// Round 3
// 321.680 us; speedup vs baseline: 2.1099x; 1.0229x over previous
//
#include <hip/hip_runtime.h>
#include <hip/hip_bf16.h>

// Batched COO SpMM: out[k, row[e], f] = sum_e values[k][e] * b[k][col[e]][f]
// B=4, NNZ=800000, M=N=50000, F=64.
//
// Round 3: counting sort now scatters ONE float4 (all 4 batch values of an
// edge) per edge instead of four 4B planar stores -> 16B scatter granularity,
// 2.5x fewer scattered stores. SpMM reads the packed float4 (broadcast) and
// unrolls 2 edges/iter for independent gather chains.

#define FEAT 64
#define SCAN_THREADS 1024

// ---------- preprocessing ----------

__global__ void hist_kernel(const int* __restrict__ rows,
                            int* __restrict__ counts, int nnz) {
    int i = blockIdx.x * blockDim.x + threadIdx.x;
    const int stride = gridDim.x * blockDim.x;
    for (; i < nnz; i += stride) atomicAdd(&counts[rows[i]], 1);
}

__global__ __launch_bounds__(SCAN_THREADS) void scan_kernel(
    const int* __restrict__ counts, int* __restrict__ row_ptr,
    int* __restrict__ cursor, int m, int nnz) {
    __shared__ int bufA[SCAN_THREADS];
    __shared__ int bufB[SCAN_THREADS];
    const int t = threadIdx.x;
    const int chunk = (m + SCAN_THREADS - 1) / SCAN_THREADS;
    const int lo = t * chunk;
    const int hi = min(lo + chunk, m);

    int s = 0;
    for (int i = lo; i < hi; ++i) s += counts[i];
    bufA[t] = s;
    __syncthreads();

    int* src = bufA;
    int* dst = bufB;
    for (int off = 1; off < SCAN_THREADS; off <<= 1) {
        int v = src[t];
        if (t >= off) v += src[t - off];
        dst[t] = v;
        __syncthreads();
        int* tmp = src; src = dst; dst = tmp;
    }

    int base = (t == 0) ? 0 : src[t - 1];
    for (int i = lo; i < hi; ++i) {
        row_ptr[i] = base;
        cursor[i]  = base;
        base += counts[i];
    }
    if (t == 0) row_ptr[m] = nnz;
}

// Counting-sort edges by row. Values for the 4 batches of an edge are packed
// into one float4 -> single 16B scattered store per edge.
__global__ void permute_kernel(const int* __restrict__ indices,
                               const float* __restrict__ values,
                               int* __restrict__ cursor,
                               int* __restrict__ col_sorted,
                               float4* __restrict__ val4_sorted, int nnz) {
    int i = blockIdx.x * blockDim.x + threadIdx.x;
    const int stride = gridDim.x * blockDim.x;
    for (; i < nnz; i += stride) {
        const int r = indices[i];
        const int c = indices[nnz + i];
        float4 v;
        v.x = values[i];
        v.y = values[(size_t)nnz + i];
        v.z = values[2 * (size_t)nnz + i];
        v.w = values[3 * (size_t)nnz + i];
        const int pos = atomicAdd(&cursor[r], 1);
        col_sorted[pos] = c;
        val4_sorted[pos] = v;
    }
}

// ---------- main SpMM (atomic-free) ----------
// One wave per row; lane = feature; 4 batch accumulators in registers.
// 2-edge unroll -> two independent col->b gather chains per iteration.
__global__ __launch_bounds__(256) void spmm_csr_kernel(
    const int* __restrict__ row_ptr, const int* __restrict__ col_sorted,
    const float4* __restrict__ val4, const float* __restrict__ b,
    float* __restrict__ out, int m) {
    const int lane = threadIdx.x & 63;
    const int wave = blockIdx.x * (blockDim.x >> 6) + (threadIdx.x >> 6);
    if (wave >= m) return;
    const int row   = wave;
    const int start = row_ptr[row];
    const int end   = row_ptr[row + 1];

    const size_t bm = (size_t)m * FEAT;
    float a0 = 0.f, a1 = 0.f, a2 = 0.f, a3 = 0.f;
    int j = start;
    for (; j + 1 < end; j += 2) {
        const int c0 = col_sorted[j];
        const int c1 = col_sorted[j + 1];
        const float4 v0 = val4[j];
        const float4 v1 = val4[j + 1];
        const size_t cb0 = (size_t)c0 * FEAT + lane;
        const size_t cb1 = (size_t)c1 * FEAT + lane;
        const float b00 = b[cb0],           b10 = b[cb1];
        const float b01 = b[bm + cb0],      b11 = b[bm + cb1];
        const float b02 = b[2 * bm + cb0],  b12 = b[2 * bm + cb1];
        const float b03 = b[3 * bm + cb0],  b13 = b[3 * bm + cb1];
        a0 += v0.x * b00 + v1.x * b10;
        a1 += v0.y * b01 + v1.y * b11;
        a2 += v0.z * b02 + v1.z * b12;
        a3 += v0.w * b03 + v1.w * b13;
    }
    if (j < end) {
        const int c = col_sorted[j];
        const float4 v = val4[j];
        const size_t cb = (size_t)c * FEAT + lane;
        a0 += v.x * b[cb];
        a1 += v.y * b[bm + cb];
        a2 += v.z * b[2 * bm + cb];
        a3 += v.w * b[3 * bm + cb];
    }
    const size_t o = (size_t)row * FEAT + lane;
    out[o]          = a0;
    out[bm + o]     = a1;
    out[2 * bm + o] = a2;
    out[3 * bm + o] = a3;
}

// ---------- fallback (round-1 atomic version, used only if ws too small) ----
__global__ __launch_bounds__(256) void spmm_atomic_kernel(
    const int* __restrict__ indices, const float* __restrict__ values,
    const float* __restrict__ b, float* __restrict__ out,
    int nnz, int m, int batch, int ntasks) {
    const int lane = threadIdx.x & 63;
    const int waves_per_block = blockDim.x >> 6;
    const int nwaves = gridDim.x * waves_per_block;
    int wave = blockIdx.x * waves_per_block + (threadIdx.x >> 6);
    for (int task = wave; task < ntasks; task += nwaves) {
        const int e = task / batch;
        const int k = task - e * batch;
        const int row = indices[e];
        const int col = indices[nnz + e];
        const float v = values[(size_t)k * nnz + e];
        const float contrib = v * b[((size_t)k * m + col) * FEAT + lane];
        unsafeAtomicAdd(&out[((size_t)k * m + row) * FEAT + lane], contrib);
    }
}

extern "C" void kernel_launch(void* const* d_in, const int* in_sizes, int n_in,
                              void* d_out, int out_size, void* d_ws, size_t ws_size,
                              hipStream_t stream) {
    const int* indices  = (const int*)d_in[0];    // [2, nnz]
    const float* values = (const float*)d_in[1];  // [batch, nnz]
    const float* b      = (const float*)d_in[4];  // [batch, m, FEAT]
    float* out          = (float*)d_out;

    const int nnz   = in_sizes[0] / 2;
    const int batch = in_sizes[1] / nnz;
    const int m     = out_size / (batch * FEAT);

    // ws layout (4B units unless noted):
    //   counts     [0, m)
    //   row_ptr    [m, 2m+1)
    //   cursor     [2m+1, 3m+1)
    //   col_sorted [3m+1, 3m+1+nnz)
    //   val4_sorted: 16B-aligned after col_sorted, nnz float4s
    const size_t need = ((size_t)3 * m + 1 + (size_t)nnz) * 4 + 16 +
                        (size_t)nnz * 16;

    if (batch != 4 || ws_size < need) {
        hipMemsetAsync(d_out, 0, (size_t)out_size * sizeof(float), stream);
        spmm_atomic_kernel<<<2048, 256, 0, stream>>>(indices, values, b, out,
                                                     nnz, m, batch, nnz * batch);
        return;
    }

    int* counts      = (int*)d_ws;
    int* row_ptr     = counts + m;
    int* cursor      = row_ptr + m + 1;
    int* col_sorted  = cursor + m;
    float4* val4_sorted =
        (float4*)(((uintptr_t)(col_sorted + nnz) + 15) & ~(uintptr_t)15);

    hipMemsetAsync(counts, 0, (size_t)m * sizeof(int), stream);
    hist_kernel<<<1024, 256, 0, stream>>>(indices, counts, nnz);
    scan_kernel<<<1, SCAN_THREADS, 0, stream>>>(counts, row_ptr, cursor, m, nnz);
    permute_kernel<<<1024, 256, 0, stream>>>(indices, values, cursor,
                                             col_sorted, val4_sorted, nnz);

    const int waves_per_block = 4;  // 256 threads
    const int grid = (m + waves_per_block - 1) / waves_per_block;
    spmm_csr_kernel<<<grid, 256, 0, stream>>>(row_ptr, col_sorted, val4_sorted,
                                              b, out, m);
}

// Round 4
// 271.846 us; speedup vs baseline: 2.4967x; 1.1833x over previous
//
#include <hip/hip_runtime.h>
#include <hip/hip_bf16.h>

// Batched COO SpMM: out[k, row[e], f] = sum_e values[k][e] * b[k][col[e]][f]
// B=4, NNZ=800000, M=N=50000, F=64.
//
// Round 4: preprocessing rewrite.
//  - hierarchical coalesced scan (3 tiny kernels) replaces the single-block
//    strided scan (was ~60-80 us of uncoalesced single-CU traffic)
//  - counting-sort scatter is now ONE int2 (col, edge_id) = 8B per edge
//  - values are then gathered into sorted order by a separate COALESCED-write
//    kernel (random reads hit L2/L3; random writes were the expensive part)
// SpMM kernel itself unchanged from round 3 (117 us, proven).

#define FEAT 64
#define SCAN_CHUNK 1024   // counts per scan block (256 threads x int4)

// ---------- preprocessing ----------

__global__ void hist_kernel(const int* __restrict__ rows,
                            int* __restrict__ counts, int nnz) {
    int i = blockIdx.x * blockDim.x + threadIdx.x;
    const int stride = gridDim.x * blockDim.x;
    for (; i < nnz; i += stride) atomicAdd(&counts[rows[i]], 1);
}

// S1: per-block sum of a 1024-count chunk (coalesced int4 reads).
__global__ __launch_bounds__(256) void scan_partial_kernel(
    const int* __restrict__ counts, int* __restrict__ blocksum, int m) {
    __shared__ int red[256];
    const int t = threadIdx.x;
    const int g = blockIdx.x * SCAN_CHUNK + t * 4;
    int s = 0;
    if (g + 3 < m) {
        const int4 c = *(const int4*)&counts[g];
        s = c.x + c.y + c.z + c.w;
    } else {
        for (int i = g; i < m; ++i) s += counts[i];
    }
    red[t] = s;
    __syncthreads();
    for (int off = 128; off; off >>= 1) {
        if (t < off) red[t] += red[t + off];
        __syncthreads();
    }
    if (t == 0) blocksum[blockIdx.x] = red[0];
}

// S2: single block scans the (<=256) block sums -> exclusive block offsets.
__global__ __launch_bounds__(256) void scan_block_kernel(
    const int* __restrict__ blocksum, int* __restrict__ blockoff,
    int nblk, int* __restrict__ row_ptr, int m, int nnz) {
    __shared__ int bufA[256];
    __shared__ int bufB[256];
    const int t = threadIdx.x;
    const int v = (t < nblk) ? blocksum[t] : 0;
    bufA[t] = v;
    __syncthreads();
    int* src = bufA;
    int* dst = bufB;
    for (int off = 1; off < 256; off <<= 1) {
        int x = src[t];
        if (t >= off) x += src[t - off];
        dst[t] = x;
        __syncthreads();
        int* tmp = src; src = dst; dst = tmp;
    }
    if (t < nblk) blockoff[t] = src[t] - v;   // exclusive
    if (t == 0) row_ptr[m] = nnz;
}

// S3: per-block LDS scan of its chunk + block offset -> row_ptr & cursor
// (coalesced int4 writes).
__global__ __launch_bounds__(256) void scan_apply_kernel(
    const int* __restrict__ counts, const int* __restrict__ blockoff,
    int* __restrict__ row_ptr, int* __restrict__ cursor, int m) {
    __shared__ int bufA[256];
    __shared__ int bufB[256];
    const int t = threadIdx.x;
    const int g = blockIdx.x * SCAN_CHUNK + t * 4;
    int c0 = 0, c1 = 0, c2 = 0, c3 = 0;
    if (g + 3 < m) {
        const int4 c = *(const int4*)&counts[g];
        c0 = c.x; c1 = c.y; c2 = c.z; c3 = c.w;
    } else {
        if (g < m)     c0 = counts[g];
        if (g + 1 < m) c1 = counts[g + 1];
        if (g + 2 < m) c2 = counts[g + 2];
    }
    const int s = c0 + c1 + c2 + c3;
    bufA[t] = s;
    __syncthreads();
    int* src = bufA;
    int* dst = bufB;
    for (int off = 1; off < 256; off <<= 1) {
        int x = src[t];
        if (t >= off) x += src[t - off];
        dst[t] = x;
        __syncthreads();
        int* tmp = src; src = dst; dst = tmp;
    }
    const int base = src[t] - s + blockoff[blockIdx.x];
    const int p0 = base, p1 = p0 + c0, p2 = p1 + c1, p3 = p2 + c2;
    if (g + 3 < m) {
        const int4 p = make_int4(p0, p1, p2, p3);
        *(int4*)&row_ptr[g] = p;
        *(int4*)&cursor[g]  = p;
    } else {
        if (g < m)     { row_ptr[g]     = p0; cursor[g]     = p0; }
        if (g + 1 < m) { row_ptr[g + 1] = p1; cursor[g + 1] = p1; }
        if (g + 2 < m) { row_ptr[g + 2] = p2; cursor[g + 2] = p2; }
    }
}

// Counting sort: scatter ONE int2 (col, edge_id) per edge.
__global__ void permute_kernel(const int* __restrict__ indices,
                               int* __restrict__ cursor,
                               int2* __restrict__ col_eid, int nnz) {
    int i = blockIdx.x * blockDim.x + threadIdx.x;
    const int stride = gridDim.x * blockDim.x;
    for (; i < nnz; i += stride) {
        const int r = indices[i];
        const int c = indices[nnz + i];
        const int pos = atomicAdd(&cursor[r], 1);
        col_eid[pos] = make_int2(c, i);
    }
}

// Gather values into sorted order: random READS (cache-friendly), coalesced
// 16B writes.
__global__ void valgather_kernel(const int2* __restrict__ col_eid,
                                 const float* __restrict__ values,
                                 float4* __restrict__ val4, int nnz) {
    int i = blockIdx.x * blockDim.x + threadIdx.x;
    const int stride = gridDim.x * blockDim.x;
    for (; i < nnz; i += stride) {
        const int e = col_eid[i].y;
        float4 v;
        v.x = values[e];
        v.y = values[(size_t)nnz + e];
        v.z = values[2 * (size_t)nnz + e];
        v.w = values[3 * (size_t)nnz + e];
        val4[i] = v;
    }
}

// ---------- main SpMM (atomic-free, unchanged structure from round 3) ------
__global__ __launch_bounds__(256) void spmm_csr_kernel(
    const int* __restrict__ row_ptr, const int2* __restrict__ col_eid,
    const float4* __restrict__ val4, const float* __restrict__ b,
    float* __restrict__ out, int m) {
    const int lane = threadIdx.x & 63;
    const int wave = blockIdx.x * (blockDim.x >> 6) + (threadIdx.x >> 6);
    if (wave >= m) return;
    const int row   = wave;
    const int start = row_ptr[row];
    const int end   = row_ptr[row + 1];

    const size_t bm = (size_t)m * FEAT;
    float a0 = 0.f, a1 = 0.f, a2 = 0.f, a3 = 0.f;
    int j = start;
    for (; j + 1 < end; j += 2) {
        const int c0 = col_eid[j].x;
        const int c1 = col_eid[j + 1].x;
        const float4 v0 = val4[j];
        const float4 v1 = val4[j + 1];
        const size_t cb0 = (size_t)c0 * FEAT + lane;
        const size_t cb1 = (size_t)c1 * FEAT + lane;
        const float b00 = b[cb0],           b10 = b[cb1];
        const float b01 = b[bm + cb0],      b11 = b[bm + cb1];
        const float b02 = b[2 * bm + cb0],  b12 = b[2 * bm + cb1];
        const float b03 = b[3 * bm + cb0],  b13 = b[3 * bm + cb1];
        a0 += v0.x * b00 + v1.x * b10;
        a1 += v0.y * b01 + v1.y * b11;
        a2 += v0.z * b02 + v1.z * b12;
        a3 += v0.w * b03 + v1.w * b13;
    }
    if (j < end) {
        const int c = col_eid[j].x;
        const float4 v = val4[j];
        const size_t cb = (size_t)c * FEAT + lane;
        a0 += v.x * b[cb];
        a1 += v.y * b[bm + cb];
        a2 += v.z * b[2 * bm + cb];
        a3 += v.w * b[3 * bm + cb];
    }
    const size_t o = (size_t)row * FEAT + lane;
    out[o]          = a0;
    out[bm + o]     = a1;
    out[2 * bm + o] = a2;
    out[3 * bm + o] = a3;
}

// ---------- fallback (round-1 atomic version) ----------
__global__ __launch_bounds__(256) void spmm_atomic_kernel(
    const int* __restrict__ indices, const float* __restrict__ values,
    const float* __restrict__ b, float* __restrict__ out,
    int nnz, int m, int batch, int ntasks) {
    const int lane = threadIdx.x & 63;
    const int waves_per_block = blockDim.x >> 6;
    const int nwaves = gridDim.x * waves_per_block;
    int wave = blockIdx.x * waves_per_block + (threadIdx.x >> 6);
    for (int task = wave; task < ntasks; task += nwaves) {
        const int e = task / batch;
        const int k = task - e * batch;
        const int row = indices[e];
        const int col = indices[nnz + e];
        const float v = values[(size_t)k * nnz + e];
        const float contrib = v * b[((size_t)k * m + col) * FEAT + lane];
        unsafeAtomicAdd(&out[((size_t)k * m + row) * FEAT + lane], contrib);
    }
}

static inline uintptr_t align16(uintptr_t p) { return (p + 15) & ~(uintptr_t)15; }

extern "C" void kernel_launch(void* const* d_in, const int* in_sizes, int n_in,
                              void* d_out, int out_size, void* d_ws, size_t ws_size,
                              hipStream_t stream) {
    const int* indices  = (const int*)d_in[0];    // [2, nnz]
    const float* values = (const float*)d_in[1];  // [batch, nnz]
    const float* b      = (const float*)d_in[4];  // [batch, m, FEAT]
    float* out          = (float*)d_out;

    const int nnz   = in_sizes[0] / 2;
    const int batch = in_sizes[1] / nnz;
    const int m     = out_size / (batch * FEAT);
    const int nblk  = (m + SCAN_CHUNK - 1) / SCAN_CHUNK;

    // ws layout, each array 16B-aligned:
    uintptr_t p = (uintptr_t)d_ws;
    int* counts      = (int*)align16(p);             p = (uintptr_t)(counts + m);
    int* row_ptr     = (int*)align16(p);             p = (uintptr_t)(row_ptr + m + 1);
    int* cursor      = (int*)align16(p);             p = (uintptr_t)(cursor + m);
    int* blocksum    = (int*)align16(p);             p = (uintptr_t)(blocksum + nblk);
    int* blockoff    = (int*)align16(p);             p = (uintptr_t)(blockoff + nblk);
    int2* col_eid    = (int2*)align16(p);            p = (uintptr_t)(col_eid + nnz);
    float4* val4     = (float4*)align16(p);          p = (uintptr_t)(val4 + nnz);
    const size_t need = p - (uintptr_t)d_ws;

    if (batch != 4 || nblk > 256 || ws_size < need) {
        hipMemsetAsync(d_out, 0, (size_t)out_size * sizeof(float), stream);
        spmm_atomic_kernel<<<2048, 256, 0, stream>>>(indices, values, b, out,
                                                     nnz, m, batch, nnz * batch);
        return;
    }

    hipMemsetAsync(counts, 0, (size_t)m * sizeof(int), stream);
    hist_kernel<<<1024, 256, 0, stream>>>(indices, counts, nnz);
    scan_partial_kernel<<<nblk, 256, 0, stream>>>(counts, blocksum, m);
    scan_block_kernel<<<1, 256, 0, stream>>>(blocksum, blockoff, nblk,
                                             row_ptr, m, nnz);
    scan_apply_kernel<<<nblk, 256, 0, stream>>>(counts, blockoff,
                                                row_ptr, cursor, m);
    permute_kernel<<<1024, 256, 0, stream>>>(indices, cursor, col_eid, nnz);
    valgather_kernel<<<1024, 256, 0, stream>>>(col_eid, values, val4, nnz);

    const int waves_per_block = 4;  // 256 threads
    const int grid = (m + waves_per_block - 1) / waves_per_block;
    spmm_csr_kernel<<<grid, 256, 0, stream>>>(row_ptr, col_eid, val4,
                                              b, out, m);
}